// Round 8
// baseline (143.316 us; speedup 1.0000x reference)
//
#include <hip/hip_runtime.h>

typedef _Float16 half_t;
typedef _Float16 hx8 __attribute__((ext_vector_type(8)));
typedef _Float16 hx4 __attribute__((ext_vector_type(4)));
typedef float fx4 __attribute__((ext_vector_type(4)));

#define LOG2E 1.44269504088896f
#define TAU 0.1f
#define NSPLIT 16

// ---------------- Kernel P: fused prep — wtrans (bx<8) + ztrans (bx>=8) -----
__global__ __launch_bounds__(256) void prep_kernel(
    const float* __restrict__ W1, const float* __restrict__ W2,
    const float* __restrict__ Z,
    half_t* __restrict__ W1t, half_t* __restrict__ W2t,
    half_t* __restrict__ Zth)
{
  __shared__ float tile[32*132];
  const int bx = blockIdx.x;
  const int tid = threadIdx.x;
  if (bx < 8) {
    const float* W = (bx & 4) ? W2 : W1;
    half_t* Wt = (bx & 4) ? W2t : W1t;
    const int i0 = (bx & 3) * 32;
    const int r = tid >> 3, cb = tid & 7;
#pragma unroll
    for (int it=0; it<4; ++it) {
      int c4 = cb*4 + it*32;
      *(fx4*)(&tile[r*132 + c4]) = *(const fx4*)(W + (size_t)(i0+r)*128 + c4);
    }
    __syncthreads();
    const int o = tid >> 1, ih = (tid & 1)*16;
    hx8 v0, v1;
#pragma unroll
    for (int u=0;u<8;++u) v0[u] = (half_t)tile[(ih+u)*132 + o];
#pragma unroll
    for (int u=0;u<8;++u) v1[u] = (half_t)tile[(ih+8+u)*132 + o];
    *(hx8*)(Wt + (size_t)o*128 + i0 + ih)     = v0;
    *(hx8*)(Wt + (size_t)o*128 + i0 + ih + 8) = v1;
  } else {
    float* zt = tile;                   // 64*36 floats
    const int b = bx - 8;
    const int nb = b >> 2;
    const int db = b & 3;
#pragma unroll
    for (int i=0;i<2;++i) {
      int fid = i*256 + tid;
      int r = fid >> 3, c4 = (fid & 7) * 4;
      *(fx4*)(&zt[r*36 + c4]) = *(const fx4*)(Z + (size_t)(nb*64 + r)*128 + db*32 + c4);
    }
    __syncthreads();
    const int cr = tid >> 3, j = tid & 7, n0 = j*8;
    hx8 hv;
#pragma unroll
    for (int idx=0;idx<8;++idx) hv[idx] = (half_t)zt[(n0+idx)*36 + cr];
    *(hx8*)(Zth + (size_t)(db*32 + cr)*8192 + nb*64 + n0) = hv;
  }
}

// ---------------- Kernel 1: T = relu(Z@W1+b1)@W2+b2 via MFMA ----------------
__global__ __launch_bounds__(128) void mlp_kernel(
    const float* __restrict__ Z, const half_t* __restrict__ W1t,
    const float* __restrict__ b1, const half_t* __restrict__ W2t,
    const float* __restrict__ b2, half_t* __restrict__ T)
{
  __shared__ half_t Hs[2][16*136];
  const int tid = threadIdx.x;
  const int w = tid >> 6, lane = tid & 63;
  const int q = lane >> 4, c = lane & 15;
  const int wrow = blockIdx.x*32 + w*16;

  hx8 zb[4];
#pragma unroll
  for (int ks=0;ks<4;++ks) {
    fx4 a = *(const fx4*)(Z + (size_t)(wrow + c)*128 + ks*32 + q*8);
    fx4 b = *(const fx4*)(Z + (size_t)(wrow + c)*128 + ks*32 + q*8 + 4);
#pragma unroll
    for (int u=0;u<4;++u) { zb[ks][u] = (half_t)a[u]; zb[ks][4+u] = (half_t)b[u]; }
  }
  fx4 acc[8];
#pragma unroll
  for (int mt=0;mt<8;++mt) acc[mt] = (fx4){0.f,0.f,0.f,0.f};
#pragma unroll
  for (int mt=0;mt<8;++mt)
#pragma unroll
    for (int ks=0;ks<4;++ks) {
      hx8 aw = *(const hx8*)(W1t + (size_t)(mt*16 + c)*128 + ks*32 + q*8);
      acc[mt] = __builtin_amdgcn_mfma_f32_16x16x32_f16(aw, zb[ks], acc[mt], 0,0,0);
    }
#pragma unroll
  for (int mt=0;mt<8;++mt) {
    fx4 bias = *(const fx4*)(b1 + mt*16 + 4*q);
    hx4 hv;
#pragma unroll
    for (int i=0;i<4;++i) {
      float h = acc[mt][i] + bias[i];
      hv[i] = (half_t)(h > 0.f ? h : 0.f);
    }
    *(hx4*)(&Hs[w][c*136 + mt*16 + 4*q]) = hv;
  }

  hx8 hb[4];
#pragma unroll
  for (int ks=0;ks<4;++ks) hb[ks] = *(const hx8*)(&Hs[w][c*136 + ks*32 + q*8]);
#pragma unroll
  for (int mt=0;mt<8;++mt) acc[mt] = (fx4){0.f,0.f,0.f,0.f};
#pragma unroll
  for (int mt=0;mt<8;++mt)
#pragma unroll
    for (int ks=0;ks<4;++ks) {
      hx8 aw = *(const hx8*)(W2t + (size_t)(mt*16 + c)*128 + ks*32 + q*8);
      acc[mt] = __builtin_amdgcn_mfma_f32_16x16x32_f16(aw, hb[ks], acc[mt], 0,0,0);
    }
#pragma unroll
  for (int mt=0;mt<8;++mt) {
    fx4 bias = *(const fx4*)(b2 + mt*16 + 4*q);
    hx4 tv;
#pragma unroll
    for (int i=0;i<4;++i) tv[i] = (half_t)(acc[mt][i] + bias[i]);
    *(hx4*)(T + (size_t)(wrow + c)*128 + mt*16 + 4*q) = tv;
  }
}

// ---------------- Kernel 3: flash attention partials ------------------------
// grid 1024 = 64 query-blocks x 16 key-splits(512 keys = 8 tiles of 64).
// LDS shrunk to 32.8 KB: Ps ALIASES Tks (dead after scores) with a 3rd barrier.
// Per-wave Ps chunk is XOR-swizzled (k ^ ((row&7)*8)) — pad-free, <=2-way
// write conflicts (free), conflict-free hx8 reads. 4 blocks/CU at VGPR 128.
// NEVER __launch_bounds__(256,3+): empirically forces 84 VGPR + scratch spill.
__global__ __launch_bounds__(256,2) void flash_kernel(
    const half_t* __restrict__ T, const half_t* __restrict__ Zt,
    half_t* __restrict__ Pacc, float* __restrict__ Pm, float* __restrict__ Pl)
{
  __shared__ half_t Tks[16*512];        // scores A-frags; after sync_c: per-wave P^T
  __shared__ half_t Zts[16*512];
  const int tid = threadIdx.x;
  const int w = tid >> 6, lane = tid & 63;
  const int q = lane >> 4, c = lane & 15;
  const int bx = blockIdx.x;
  const int qb = bx >> 4, kh = bx & 15;
  const int wrow = qb*128 + w*32;
  half_t* Psw = &Tks[w*2048];           // 32 rows x 64 keys, xor-swizzled
  const int sw = (c & 7) * 8;           // xor swizzle term (same for rows c and 16+c)

  hx8 bq[2][4];
#pragma unroll
  for (int nt=0;nt<2;++nt)
#pragma unroll
    for (int ks=0;ks<4;++ks)
      bq[nt][ks] = *(const hx8*)(T + (size_t)(wrow + nt*16 + c)*128 + ks*32 + q*8);

  fx4 oacc[8][2];
#pragma unroll
  for (int mtd=0;mtd<8;++mtd)
#pragma unroll
    for (int nt=0;nt<2;++nt) oacc[mtd][nt] = (fx4){0.f,0.f,0.f,0.f};
  float m_run[2] = {-1e30f,-1e30f};
  float l_run[2] = {0.f,0.f};

  hx8 pre[8];
  const int kbase = kh*512;

  auto load_tile = [&](int kt0) {
    if (w < 2) {
#pragma unroll
      for (int i=0;i<8;++i) {
        int f = w*8 + i, mt = f >> 2, ks = f & 3;
        pre[i] = *(const hx8*)(T + (size_t)(kt0 + mt*16 + c)*128 + ks*32 + q*8);
      }
    } else {
#pragma unroll
      for (int i=0;i<8;++i) {
        int f2 = (w-2)*8 + i, mtd = f2 >> 1, ks2 = f2 & 1;
        pre[i] = *(const hx8*)(Zt + (size_t)(mtd*16 + c)*8192 + kt0 + ks2*32 + q*8);
      }
    }
  };
  auto store_tile = [&]() {
    if (w < 2) {
#pragma unroll
      for (int i=0;i<8;++i) { int f = w*8 + i; *(hx8*)(&Tks[f*512 + lane*8]) = pre[i]; }
    } else {
#pragma unroll
      for (int i=0;i<8;++i) { int f2 = (w-2)*8 + i; *(hx8*)(&Zts[f2*512 + lane*8]) = pre[i]; }
    }
  };

  load_tile(kbase);
  for (int t=0;t<8;++t) {
    __syncthreads();                    // sync_a: prior PV's Ps/Zts reads done
    store_tile();
    __syncthreads();                    // sync_b: tile t staged
    if (t < 7) load_tile(kbase + (t+1)*64);

    // ---- scores: St[64 keys x 32 queries] (reads Tks) ----
    fx4 sacc[4][2];
#pragma unroll
    for (int mt=0;mt<4;++mt)
#pragma unroll
      for (int nt=0;nt<2;++nt) sacc[mt][nt] = (fx4){0.f,0.f,0.f,0.f};
#pragma unroll
    for (int ks=0;ks<4;++ks)
#pragma unroll
      for (int mt=0;mt<4;++mt) {
        hx8 ak = *(const hx8*)(&Tks[(mt*4+ks)*512 + lane*8]);
        sacc[mt][0] = __builtin_amdgcn_mfma_f32_16x16x32_f16(ak, bq[0][ks], sacc[mt][0], 0,0,0);
        sacc[mt][1] = __builtin_amdgcn_mfma_f32_16x16x32_f16(ak, bq[1][ks], sacc[mt][1], 0,0,0);
      }

    // ---- online softmax per query column; P packed into registers ----
    hx4 pk[2][4];
#pragma unroll
    for (int nt=0;nt<2;++nt) {
      float mx = -1e30f;
#pragma unroll
      for (int mt=0;mt<4;++mt)
#pragma unroll
        for (int i=0;i<4;++i) mx = fmaxf(mx, sacc[mt][nt][i]);
      mx = fmaxf(mx, __shfl_xor(mx, 16, 64));
      mx = fmaxf(mx, __shfl_xor(mx, 32, 64));
      float mnew = fmaxf(m_run[nt], mx);
      float alpha = __builtin_amdgcn_exp2f((m_run[nt]-mnew)*LOG2E);
      m_run[nt] = mnew;
      float nb = mnew*LOG2E;
      float rs = 0.f;
#pragma unroll
      for (int mt=0;mt<4;++mt) {
#pragma unroll
        for (int i=0;i<4;++i) {
          float p = __builtin_amdgcn_exp2f(sacc[mt][nt][i]*LOG2E - nb);
          rs += p;
          pk[nt][mt][i] = (half_t)p;
        }
      }
      rs += __shfl_xor(rs, 16, 64);
      rs += __shfl_xor(rs, 32, 64);
      l_run[nt] = l_run[nt]*alpha + rs;
#pragma unroll
      for (int mtd=0;mtd<8;++mtd)
#pragma unroll
        for (int i=0;i<4;++i) oacc[mtd][nt][i] *= alpha;
    }

    __syncthreads();                    // sync_c: all scores reads of Tks done
    // write P^T into the (now dead) Tks region, per-wave, xor-swizzled
#pragma unroll
    for (int nt=0;nt<2;++nt)
#pragma unroll
      for (int mt=0;mt<4;++mt)
        *(hx4*)(&Psw[(nt*16 + c)*64 + ((mt*16 + 4*q) ^ sw)]) = pk[nt][mt];

    // ---- PV: O^T += Zt_tile @ P^T ----
#pragma unroll
    for (int ks2=0;ks2<2;++ks2) {
      hx8 bp0 = *(const hx8*)(&Psw[(c     )*64 + ((ks2*32 + q*8) ^ sw)]);
      hx8 bp1 = *(const hx8*)(&Psw[(16 + c)*64 + ((ks2*32 + q*8) ^ sw)]);
#pragma unroll
      for (int mtd=0;mtd<8;++mtd) {
        hx8 az = *(const hx8*)(&Zts[(mtd*2+ks2)*512 + lane*8]);
        oacc[mtd][0] = __builtin_amdgcn_mfma_f32_16x16x32_f16(az, bp0, oacc[mtd][0], 0,0,0);
        oacc[mtd][1] = __builtin_amdgcn_mfma_f32_16x16x32_f16(az, bp1, oacc[mtd][1], 0,0,0);
      }
    }
  }

#pragma unroll
  for (int nt=0;nt<2;++nt) {
    float inv = 1.0f / l_run[nt];
    const size_t rowg = (size_t)(bx*128 + w*32 + nt*16 + c);
#pragma unroll
    for (int mtd=0;mtd<8;++mtd) {
      hx4 ov;
#pragma unroll
      for (int i=0;i<4;++i) ov[i] = (half_t)(oacc[mtd][nt][i]*inv);
      *(hx4*)(Pacc + rowg*128 + mtd*16 + 4*q) = ov;
    }
    if (q == 0) {
      Pm[rowg] = m_run[nt];
      Pl[rowg] = l_run[nt];
    }
  }
}

// ---------------- Kernel 4: merge NSPLIT key-split partials ----------------
__global__ __launch_bounds__(256) void merge_kernel(
    const float* __restrict__ Z, const half_t* __restrict__ Pacc,
    const float* __restrict__ Pm, const float* __restrict__ Pl,
    float* __restrict__ out)
{
  const int th = blockIdx.x*256 + threadIdx.x;
  const int r = th >> 5, cg = th & 31;
  const int qb = r >> 7, rr = r & 127;
  float mk[NSPLIT], lk[NSPLIT];
  float M = -1e30f;
#pragma unroll
  for (int k=0;k<NSPLIT;++k) {
    int p = qb*NSPLIT + k;
    mk[k] = Pm[p*128 + rr];
    lk[k] = Pl[p*128 + rr];
    M = fmaxf(M, mk[k]);
  }
  float L = 0.f, wk[NSPLIT];
#pragma unroll
  for (int k=0;k<NSPLIT;++k) { wk[k] = lk[k]*__builtin_amdgcn_exp2f((mk[k]-M)*LOG2E); L += wk[k]; }
  float o0=0.f,o1=0.f,o2=0.f,o3=0.f;
#pragma unroll
  for (int k=0;k<NSPLIT;++k) {
    int p = qb*NSPLIT + k;
    hx4 v = *(const hx4*)(Pacc + ((size_t)p*128 + rr)*128 + cg*4);
    o0 += wk[k]*(float)v[0]; o1 += wk[k]*(float)v[1];
    o2 += wk[k]*(float)v[2]; o3 += wk[k]*(float)v[3];
  }
  float invL = 1.0f / L;
  fx4 zv = *(const fx4*)(Z + (size_t)r*128 + cg*4);
  fx4 res;
  res[0] = (1.f-TAU)*zv[0] + TAU*o0*invL;
  res[1] = (1.f-TAU)*zv[1] + TAU*o1*invL;
  res[2] = (1.f-TAU)*zv[2] + TAU*o2*invL;
  res[3] = (1.f-TAU)*zv[3] + TAU*o3*invL;
  *(fx4*)(out + (size_t)r*128 + cg*4) = res;
}

extern "C" void kernel_launch(void* const* d_in, const int* in_sizes, int n_in,
                              void* d_out, int out_size, void* d_ws, size_t ws_size,
                              hipStream_t stream) {
  const float* Z  = (const float*)d_in[0];
  const float* W1 = (const float*)d_in[1];
  const float* b1 = (const float*)d_in[2];
  const float* W2 = (const float*)d_in[3];
  const float* b2 = (const float*)d_in[4];
  float* out = (float*)d_out;

  char* ws = (char*)d_ws;
  const size_t NBLK = 64 * NSPLIT;                                // 1024
  half_t* Thi  = (half_t*)(ws);                                   // 2 MB
  half_t* Zth  = (half_t*)(ws + (size_t)2*1024*1024);             // 2 MB
  half_t* Pacc = (half_t*)(ws + (size_t)4*1024*1024);             // 32 MB
  float*  Pm   = (float*)(ws + (size_t)4*1024*1024 + NBLK*128*128*2);
  float*  Pl   = Pm + NBLK*128;
  half_t* W1t  = (half_t*)(ws + (size_t)4*1024*1024 + NBLK*128*128*2 + 2*NBLK*128*4);
  half_t* W2t  = W1t + 128*128;

  hipLaunchKernelGGL(prep_kernel,  dim3(520),  dim3(256), 0, stream, W1, W2, Z, W1t, W2t, Zth);
  hipLaunchKernelGGL(mlp_kernel,   dim3(256),  dim3(128), 0, stream, Z, W1t, b1, W2t, b2, Thi);
  hipLaunchKernelGGL(flash_kernel, dim3(NBLK), dim3(256), 0, stream, Thi, Zth, Pacc, Pm, Pl);
  hipLaunchKernelGGL(merge_kernel, dim3(1024), dim3(256), 0, stream, Z, Pacc, Pm, Pl, out);
}

// Round 9
// 131.627 us; speedup vs baseline: 1.0888x; 1.0888x over previous
//
#include <hip/hip_runtime.h>

typedef _Float16 half_t;
typedef _Float16 hx8 __attribute__((ext_vector_type(8)));
typedef _Float16 hx4 __attribute__((ext_vector_type(4)));
typedef float fx4 __attribute__((ext_vector_type(4)));

#define LOG2E 1.44269504088896f
#define TAU 0.1f
#define NSPLIT 8

// ---------------- Kernel P: fused prep — wtrans (bx<8) + ztrans (bx>=8) -----
__global__ __launch_bounds__(256) void prep_kernel(
    const float* __restrict__ W1, const float* __restrict__ W2,
    const float* __restrict__ Z,
    half_t* __restrict__ W1t, half_t* __restrict__ W2t,
    half_t* __restrict__ Zth)
{
  __shared__ float tile[32*132];
  const int bx = blockIdx.x;
  const int tid = threadIdx.x;
  if (bx < 8) {
    const float* W = (bx & 4) ? W2 : W1;
    half_t* Wt = (bx & 4) ? W2t : W1t;
    const int i0 = (bx & 3) * 32;
    const int r = tid >> 3, cb = tid & 7;
#pragma unroll
    for (int it=0; it<4; ++it) {
      int c4 = cb*4 + it*32;
      *(fx4*)(&tile[r*132 + c4]) = *(const fx4*)(W + (size_t)(i0+r)*128 + c4);
    }
    __syncthreads();
    const int o = tid >> 1, ih = (tid & 1)*16;
    hx8 v0, v1;
#pragma unroll
    for (int u=0;u<8;++u) v0[u] = (half_t)tile[(ih+u)*132 + o];
#pragma unroll
    for (int u=0;u<8;++u) v1[u] = (half_t)tile[(ih+8+u)*132 + o];
    *(hx8*)(Wt + (size_t)o*128 + i0 + ih)     = v0;
    *(hx8*)(Wt + (size_t)o*128 + i0 + ih + 8) = v1;
  } else {
    float* zt = tile;                   // 64*36 floats
    const int b = bx - 8;
    const int nb = b >> 2;
    const int db = b & 3;
#pragma unroll
    for (int i=0;i<2;++i) {
      int fid = i*256 + tid;
      int r = fid >> 3, c4 = (fid & 7) * 4;
      *(fx4*)(&zt[r*36 + c4]) = *(const fx4*)(Z + (size_t)(nb*64 + r)*128 + db*32 + c4);
    }
    __syncthreads();
    const int cr = tid >> 3, j = tid & 7, n0 = j*8;
    hx8 hv;
#pragma unroll
    for (int idx=0;idx<8;++idx) hv[idx] = (half_t)zt[(n0+idx)*36 + cr];
    *(hx8*)(Zth + (size_t)(db*32 + cr)*8192 + nb*64 + n0) = hv;
  }
}

// ---------------- Kernel 1: T = relu(Z@W1+b1)@W2+b2 via MFMA ----------------
__global__ __launch_bounds__(128) void mlp_kernel(
    const float* __restrict__ Z, const half_t* __restrict__ W1t,
    const float* __restrict__ b1, const half_t* __restrict__ W2t,
    const float* __restrict__ b2, half_t* __restrict__ T)
{
  __shared__ half_t Hs[2][16*136];
  const int tid = threadIdx.x;
  const int w = tid >> 6, lane = tid & 63;
  const int q = lane >> 4, c = lane & 15;
  const int wrow = blockIdx.x*32 + w*16;

  hx8 zb[4];
#pragma unroll
  for (int ks=0;ks<4;++ks) {
    fx4 a = *(const fx4*)(Z + (size_t)(wrow + c)*128 + ks*32 + q*8);
    fx4 b = *(const fx4*)(Z + (size_t)(wrow + c)*128 + ks*32 + q*8 + 4);
#pragma unroll
    for (int u=0;u<4;++u) { zb[ks][u] = (half_t)a[u]; zb[ks][4+u] = (half_t)b[u]; }
  }
  fx4 acc[8];
#pragma unroll
  for (int mt=0;mt<8;++mt) acc[mt] = (fx4){0.f,0.f,0.f,0.f};
#pragma unroll
  for (int mt=0;mt<8;++mt)
#pragma unroll
    for (int ks=0;ks<4;++ks) {
      hx8 aw = *(const hx8*)(W1t + (size_t)(mt*16 + c)*128 + ks*32 + q*8);
      acc[mt] = __builtin_amdgcn_mfma_f32_16x16x32_f16(aw, zb[ks], acc[mt], 0,0,0);
    }
#pragma unroll
  for (int mt=0;mt<8;++mt) {
    fx4 bias = *(const fx4*)(b1 + mt*16 + 4*q);
    hx4 hv;
#pragma unroll
    for (int i=0;i<4;++i) {
      float h = acc[mt][i] + bias[i];
      hv[i] = (half_t)(h > 0.f ? h : 0.f);
    }
    *(hx4*)(&Hs[w][c*136 + mt*16 + 4*q]) = hv;
  }

  hx8 hb[4];
#pragma unroll
  for (int ks=0;ks<4;++ks) hb[ks] = *(const hx8*)(&Hs[w][c*136 + ks*32 + q*8]);
#pragma unroll
  for (int mt=0;mt<8;++mt) acc[mt] = (fx4){0.f,0.f,0.f,0.f};
#pragma unroll
  for (int mt=0;mt<8;++mt)
#pragma unroll
    for (int ks=0;ks<4;++ks) {
      hx8 aw = *(const hx8*)(W2t + (size_t)(mt*16 + c)*128 + ks*32 + q*8);
      acc[mt] = __builtin_amdgcn_mfma_f32_16x16x32_f16(aw, hb[ks], acc[mt], 0,0,0);
    }
#pragma unroll
  for (int mt=0;mt<8;++mt) {
    fx4 bias = *(const fx4*)(b2 + mt*16 + 4*q);
    hx4 tv;
#pragma unroll
    for (int i=0;i<4;++i) tv[i] = (half_t)(acc[mt][i] + bias[i]);
    *(hx4*)(T + (size_t)(wrow + c)*128 + mt*16 + 4*q) = tv;
  }
}

// ---------------- Kernel 3: flash attention partials ------------------------
// grid 512 = 64 query-blocks x 8 key-splits(1024 keys = 16 tiles of 64).
// Async-DMA pipeline: double-buffered Tks/Zts (64 KB LDS) filled with
// global_load_lds width-16 (frag-linear layout == uniform base + lane*16B).
// Loads for tile t+1 issue mid-tile (after sync_c); the NEXT top-barrier's
// implicit vmcnt(0) drains them after ~700 cyc of softmax+PV cover.
// Ps aliases the scores-dead current Tks buffer (R8-verified xor swizzle).
// 2 barriers/tile, zero staging VGPRs, zero ds_write staging instructions.
// NEVER __launch_bounds__(256,3+): empirically forces 84 VGPR + scratch spill.
__global__ __launch_bounds__(256,2) void flash_kernel(
    const half_t* __restrict__ T, const half_t* __restrict__ Zt,
    half_t* __restrict__ Pacc, float* __restrict__ Pm, float* __restrict__ Pl)
{
  __shared__ half_t Tbuf[2][16*512];    // 32 KB
  __shared__ half_t Zbuf[2][16*512];    // 32 KB  (total 64 KB = static max)
  const int tid = threadIdx.x;
  const int w = tid >> 6, lane = tid & 63;
  const int q = lane >> 4, c = lane & 15;
  const int bx = blockIdx.x;
  const int qb = bx >> 3, kh = bx & 7;
  const int wrow = qb*128 + w*32;
  const int sw = (c & 7) * 8;           // Ps xor-swizzle term

  hx8 bq[2][4];
#pragma unroll
  for (int nt=0;nt<2;++nt)
#pragma unroll
    for (int ks=0;ks<4;++ks)
      bq[nt][ks] = *(const hx8*)(T + (size_t)(wrow + nt*16 + c)*128 + ks*32 + q*8);

  fx4 oacc[8][2];
#pragma unroll
  for (int mtd=0;mtd<8;++mtd)
#pragma unroll
    for (int nt=0;nt<2;++nt) oacc[mtd][nt] = (fx4){0.f,0.f,0.f,0.f};
  float m_run[2] = {-1e30f,-1e30f};
  float l_run[2] = {0.f,0.f};

  const int kbase = kh*1024;

  // wave-uniform fragment ownership: waves 0,1 fill Tbuf; waves 2,3 fill Zbuf
  auto issue_loads = [&](int kt0, int b) {
    if (w < 2) {
#pragma unroll
      for (int i=0;i<8;++i) {
        int f = w*8 + i, mt = f >> 2, ks = f & 3;
        const half_t* gp = T + (size_t)(kt0 + mt*16 + c)*128 + ks*32 + q*8;
        half_t* lp = &Tbuf[b][f*512 + lane*8];
        __builtin_amdgcn_global_load_lds(
            (const __attribute__((address_space(1))) void*)gp,
            (__attribute__((address_space(3))) void*)lp, 16, 0, 0);
      }
    } else {
#pragma unroll
      for (int i=0;i<8;++i) {
        int f2 = (w-2)*8 + i, mtd = f2 >> 1, ks2 = f2 & 1;
        const half_t* gp = Zt + (size_t)(mtd*16 + c)*8192 + kt0 + ks2*32 + q*8;
        half_t* lp = &Zbuf[b][f2*512 + lane*8];
        __builtin_amdgcn_global_load_lds(
            (const __attribute__((address_space(1))) void*)gp,
            (__attribute__((address_space(3))) void*)lp, 16, 0, 0);
      }
    }
  };

  issue_loads(kbase, 0);

  for (int t=0;t<16;++t) {
    const int cur = t & 1;
    __syncthreads();                    // drains own vmcnt (fills of cur) +
                                        // publishes; prior readers of cur done
    half_t* Tcur = Tbuf[cur];
    half_t* Zcur = Zbuf[cur];
    half_t* Psw  = &Tbuf[cur][w*2048];  // per-wave 4 KB, aliased post-scores

    // ---- scores: St[64 keys x 32 queries] ----
    fx4 sacc[4][2];
#pragma unroll
    for (int mt=0;mt<4;++mt)
#pragma unroll
      for (int nt=0;nt<2;++nt) sacc[mt][nt] = (fx4){0.f,0.f,0.f,0.f};
#pragma unroll
    for (int ks=0;ks<4;++ks)
#pragma unroll
      for (int mt=0;mt<4;++mt) {
        hx8 ak = *(const hx8*)(&Tcur[(mt*4+ks)*512 + lane*8]);
        sacc[mt][0] = __builtin_amdgcn_mfma_f32_16x16x32_f16(ak, bq[0][ks], sacc[mt][0], 0,0,0);
        sacc[mt][1] = __builtin_amdgcn_mfma_f32_16x16x32_f16(ak, bq[1][ks], sacc[mt][1], 0,0,0);
      }

    // ---- online softmax per query column; P packed into registers ----
    hx4 pk[2][4];
#pragma unroll
    for (int nt=0;nt<2;++nt) {
      float mx = -1e30f;
#pragma unroll
      for (int mt=0;mt<4;++mt)
#pragma unroll
        for (int i=0;i<4;++i) mx = fmaxf(mx, sacc[mt][nt][i]);
      mx = fmaxf(mx, __shfl_xor(mx, 16, 64));
      mx = fmaxf(mx, __shfl_xor(mx, 32, 64));
      float mnew = fmaxf(m_run[nt], mx);
      float alpha = __builtin_amdgcn_exp2f((m_run[nt]-mnew)*LOG2E);
      m_run[nt] = mnew;
      float nb = mnew*LOG2E;
      float rs = 0.f;
#pragma unroll
      for (int mt=0;mt<4;++mt) {
#pragma unroll
        for (int i=0;i<4;++i) {
          float p = __builtin_amdgcn_exp2f(sacc[mt][nt][i]*LOG2E - nb);
          rs += p;
          pk[nt][mt][i] = (half_t)p;
        }
      }
      rs += __shfl_xor(rs, 16, 64);
      rs += __shfl_xor(rs, 32, 64);
      l_run[nt] = l_run[nt]*alpha + rs;
#pragma unroll
      for (int mtd=0;mtd<8;++mtd)
#pragma unroll
        for (int i=0;i<4;++i) oacc[mtd][nt][i] *= alpha;
    }

    __syncthreads();                    // sync_c: all scores reads of Tcur done
    if (t < 15) issue_loads(kbase + (t+1)*64, cur ^ 1);  // async fill next buf

    // write P^T into the (now dead) Tcur region, per-wave, xor-swizzled
#pragma unroll
    for (int nt=0;nt<2;++nt)
#pragma unroll
      for (int mt=0;mt<4;++mt)
        *(hx4*)(&Psw[(nt*16 + c)*64 + ((mt*16 + 4*q) ^ sw)]) = pk[nt][mt];

    // ---- PV: O^T += Zt_tile @ P^T ----
#pragma unroll
    for (int ks2=0;ks2<2;++ks2) {
      hx8 bp0 = *(const hx8*)(&Psw[(c     )*64 + ((ks2*32 + q*8) ^ sw)]);
      hx8 bp1 = *(const hx8*)(&Psw[(16 + c)*64 + ((ks2*32 + q*8) ^ sw)]);
#pragma unroll
      for (int mtd=0;mtd<8;++mtd) {
        hx8 az = *(const hx8*)(&Zcur[(mtd*2+ks2)*512 + lane*8]);
        oacc[mtd][0] = __builtin_amdgcn_mfma_f32_16x16x32_f16(az, bp0, oacc[mtd][0], 0,0,0);
        oacc[mtd][1] = __builtin_amdgcn_mfma_f32_16x16x32_f16(az, bp1, oacc[mtd][1], 0,0,0);
      }
    }
  }

#pragma unroll
  for (int nt=0;nt<2;++nt) {
    float inv = 1.0f / l_run[nt];
    const size_t rowg = (size_t)(bx*128 + w*32 + nt*16 + c);
#pragma unroll
    for (int mtd=0;mtd<8;++mtd) {
      hx4 ov;
#pragma unroll
      for (int i=0;i<4;++i) ov[i] = (half_t)(oacc[mtd][nt][i]*inv);
      *(hx4*)(Pacc + rowg*128 + mtd*16 + 4*q) = ov;
    }
    if (q == 0) {
      Pm[rowg] = m_run[nt];
      Pl[rowg] = l_run[nt];
    }
  }
}

// ---------------- Kernel 4: merge NSPLIT key-split partials ----------------
__global__ __launch_bounds__(256) void merge_kernel(
    const float* __restrict__ Z, const half_t* __restrict__ Pacc,
    const float* __restrict__ Pm, const float* __restrict__ Pl,
    float* __restrict__ out)
{
  const int th = blockIdx.x*256 + threadIdx.x;
  const int r = th >> 5, cg = th & 31;
  const int qb = r >> 7, rr = r & 127;
  float mk[NSPLIT], lk[NSPLIT];
  float M = -1e30f;
#pragma unroll
  for (int k=0;k<NSPLIT;++k) {
    int p = qb*NSPLIT + k;
    mk[k] = Pm[p*128 + rr];
    lk[k] = Pl[p*128 + rr];
    M = fmaxf(M, mk[k]);
  }
  float L = 0.f, wk[NSPLIT];
#pragma unroll
  for (int k=0;k<NSPLIT;++k) { wk[k] = lk[k]*__builtin_amdgcn_exp2f((mk[k]-M)*LOG2E); L += wk[k]; }
  float o0=0.f,o1=0.f,o2=0.f,o3=0.f;
#pragma unroll
  for (int k=0;k<NSPLIT;++k) {
    int p = qb*NSPLIT + k;
    hx4 v = *(const hx4*)(Pacc + ((size_t)p*128 + rr)*128 + cg*4);
    o0 += wk[k]*(float)v[0]; o1 += wk[k]*(float)v[1];
    o2 += wk[k]*(float)v[2]; o3 += wk[k]*(float)v[3];
  }
  float invL = 1.0f / L;
  fx4 zv = *(const fx4*)(Z + (size_t)r*128 + cg*4);
  fx4 res;
  res[0] = (1.f-TAU)*zv[0] + TAU*o0*invL;
  res[1] = (1.f-TAU)*zv[1] + TAU*o1*invL;
  res[2] = (1.f-TAU)*zv[2] + TAU*o2*invL;
  res[3] = (1.f-TAU)*zv[3] + TAU*o3*invL;
  *(fx4*)(out + (size_t)r*128 + cg*4) = res;
}

extern "C" void kernel_launch(void* const* d_in, const int* in_sizes, int n_in,
                              void* d_out, int out_size, void* d_ws, size_t ws_size,
                              hipStream_t stream) {
  const float* Z  = (const float*)d_in[0];
  const float* W1 = (const float*)d_in[1];
  const float* b1 = (const float*)d_in[2];
  const float* W2 = (const float*)d_in[3];
  const float* b2 = (const float*)d_in[4];
  float* out = (float*)d_out;

  char* ws = (char*)d_ws;
  const size_t NBLK = 64 * NSPLIT;                                // 512
  half_t* Thi  = (half_t*)(ws);                                   // 2 MB
  half_t* Zth  = (half_t*)(ws + (size_t)2*1024*1024);             // 2 MB
  half_t* Pacc = (half_t*)(ws + (size_t)4*1024*1024);             // 16 MB
  float*  Pm   = (float*)(ws + (size_t)4*1024*1024 + NBLK*128*128*2);
  float*  Pl   = Pm + NBLK*128;
  half_t* W1t  = (half_t*)(ws + (size_t)4*1024*1024 + NBLK*128*128*2 + 2*NBLK*128*4);
  half_t* W2t  = W1t + 128*128;

  hipLaunchKernelGGL(prep_kernel,  dim3(520),  dim3(256), 0, stream, W1, W2, Z, W1t, W2t, Zth);
  hipLaunchKernelGGL(mlp_kernel,   dim3(256),  dim3(128), 0, stream, Z, W1t, b1, W2t, b2, Thi);
  hipLaunchKernelGGL(flash_kernel, dim3(NBLK), dim3(256), 0, stream, Thi, Zth, Pacc, Pm, Pl);
  hipLaunchKernelGGL(merge_kernel, dim3(1024), dim3(256), 0, stream, Z, Pacc, Pm, Pl, out);
}